// Round 4
// baseline (16611.595 us; speedup 1.0000x reference)
//
#include <hip/hip_runtime.h>

#define B_ 16
#define T_ 256
#define E_ 512
#define H_ 1024
#define V_ 32000

typedef float f32x4 __attribute__((ext_vector_type(4)));
typedef short short8 __attribute__((ext_vector_type(8)));

__device__ __forceinline__ unsigned short f2bf(float x) {
    unsigned int u = __float_as_uint(x);
    u += 0x7FFF + ((u >> 16) & 1);            // RTNE
    return (unsigned short)(u >> 16);
}
__device__ __forceinline__ float bf2f(unsigned short b) {
    return __uint_as_float(((unsigned int)b) << 16);
}

// ---------------------------------------------------------------------------
// Embedding gather fused with bf16 hi/lo split: emb[tokens] -> Ah/Al [4096,512]
// ---------------------------------------------------------------------------
__global__ __launch_bounds__(256)
void gather_cvt_k(const int* __restrict__ tokens, const float* __restrict__ emb,
                  unsigned short* __restrict__ Ah, unsigned short* __restrict__ Al)
{
    int i  = blockIdx.x * 256 + threadIdx.x;   // float4 id; 4096*128 total
    int bt = i >> 7;
    int e4 = i & 127;
    float4 v = ((const float4*)(emb + (size_t)tokens[bt] * E_))[e4];
    ushort4 h, l;
    h.x = f2bf(v.x); l.x = f2bf(v.x - bf2f(h.x));
    h.y = f2bf(v.y); l.y = f2bf(v.y - bf2f(h.y));
    h.z = f2bf(v.z); l.z = f2bf(v.z - bf2f(h.z));
    h.w = f2bf(v.w); l.w = f2bf(v.w - bf2f(h.w));
    ((ushort4*)Ah)[i] = h;
    ((ushort4*)Al)[i] = l;
}

// ---------------------------------------------------------------------------
// fp32 -> bf16 hi/lo split (A activations, row-major [M][K], no transpose)
// ---------------------------------------------------------------------------
__global__ __launch_bounds__(256)
void cvt_k(const float* __restrict__ A, unsigned short* __restrict__ Ah,
           unsigned short* __restrict__ Al)
{
    int i = blockIdx.x * 256 + threadIdx.x;    // float4 id
    float4 v = ((const float4*)A)[i];
    ushort4 h, l;
    h.x = f2bf(v.x); l.x = f2bf(v.x - bf2f(h.x));
    h.y = f2bf(v.y); l.y = f2bf(v.y - bf2f(h.y));
    h.z = f2bf(v.z); l.z = f2bf(v.z - bf2f(h.z));
    h.w = f2bf(v.w); l.w = f2bf(v.w - bf2f(h.w));
    ((ushort4*)Ah)[i] = h;
    ((ushort4*)Al)[i] = l;
}

// ---------------------------------------------------------------------------
// Weight transpose + split: W fp32 [K][Nfull], col slice [n0, n0+NS) ->
// Bh/Bl bf16 [NS][K]. 32x32 LDS tiles, +1 pad, coalesced both sides.
// ---------------------------------------------------------------------------
__global__ __launch_bounds__(256)
void twz_k(const float* __restrict__ W, unsigned short* __restrict__ Bh,
           unsigned short* __restrict__ Bl, int Kd, int Nfull, int n0)
{
    __shared__ float tile[32][33];
    int t  = threadIdx.x;
    int tx = t & 31, ty = t >> 5;              // ty 0..7
    int nb = blockIdx.x * 32, kb = blockIdx.y * 32;
    #pragma unroll
    for (int i = 0; i < 4; ++i)
        tile[ty + i * 8][tx] = W[(size_t)(kb + ty + i * 8) * Nfull + n0 + nb + tx];
    __syncthreads();
    #pragma unroll
    for (int i = 0; i < 4; ++i) {
        float v = tile[tx][ty + i * 8];
        unsigned short h = f2bf(v), l = f2bf(v - bf2f(h));
        size_t o = (size_t)(nb + ty + i * 8) * Kd + kb + tx;
        Bh[o] = h; Bl[o] = l;
    }
}

// ---------------------------------------------------------------------------
// Split-bf16 3-pass MFMA GEMM: C[M, ldc] slice = A[M,K] @ B^T[NS,K] + bias.
// A given as hi/lo bf16 planes [M][K]; B as hi/lo bf16 planes [NS][K]
// (pre-transposed). 128x128 tile, BK=64, 4 waves, each wave 64x64 via
// 16x16x32 MFMA. acc += Ah*Bh + Ah*Bl + Al*Bh. XOR-swizzled LDS (16B units).
// DO_MASK: rows with tokens[row]==0 -> one-hot(global col 0).
// ---------------------------------------------------------------------------
template<int DO_MASK>
__global__ __launch_bounds__(256)
void mgemm_k(const unsigned short* __restrict__ Ah, const unsigned short* __restrict__ Al,
             const unsigned short* __restrict__ Bh, const unsigned short* __restrict__ Bl,
             const float* __restrict__ bias, float* __restrict__ C,
             const int* __restrict__ tokens, int K, int ldc, int n0)
{
    __shared__ unsigned short As[2][128 * 64];  // [plane][m*64+k] swizzled
    __shared__ unsigned short Bs[2][128 * 64];  // [plane][n*64+k] swizzled

    const int tid  = threadIdx.x;
    const int bm   = blockIdx.y * 128;
    const int bn   = blockIdx.x * 128;
    const int w    = tid >> 6, lane = tid & 63;
    const int wm   = (w >> 1) * 64, wn = (w & 1) * 64;
    const int l15  = lane & 15, lhi = lane >> 4;

    f32x4 acc[4][4];
    #pragma unroll
    for (int mi = 0; mi < 4; ++mi)
        #pragma unroll
        for (int ni = 0; ni < 4; ++ni) {
            f32x4 z = {0.f, 0.f, 0.f, 0.f};
            acc[mi][ni] = z;
        }

    for (int kt = 0; kt < K; kt += 64) {
        uint4 ra[2][4], rb[2][4];
        #pragma unroll
        for (int i = 0; i < 4; ++i) {
            int c = tid + i * 256, row = c >> 3, s = c & 7;
            size_t ga = (size_t)(bm + row) * K + kt + s * 8;
            size_t gb = (size_t)(bn + row) * K + kt + s * 8;
            ra[0][i] = *(const uint4*)(Ah + ga);
            ra[1][i] = *(const uint4*)(Al + ga);
            rb[0][i] = *(const uint4*)(Bh + gb);
            rb[1][i] = *(const uint4*)(Bl + gb);
        }
        __syncthreads();
        #pragma unroll
        for (int i = 0; i < 4; ++i) {
            int c = tid + i * 256, row = c >> 3, s = c & 7;
            int off = row * 64 + ((s ^ (row & 7)) * 8);
            *(uint4*)(&As[0][off]) = ra[0][i];
            *(uint4*)(&As[1][off]) = ra[1][i];
            *(uint4*)(&Bs[0][off]) = rb[0][i];
            *(uint4*)(&Bs[1][off]) = rb[1][i];
        }
        __syncthreads();
        #pragma unroll
        for (int ks = 0; ks < 2; ++ks) {
            short8 ah[4], al[4], bh[4], bl[4];
            const int s = ks * 4 + lhi;
            #pragma unroll
            for (int mi = 0; mi < 4; ++mi) {
                int m = wm + mi * 16 + l15;
                int off = m * 64 + ((s ^ (m & 7)) * 8);
                ah[mi] = *(const short8*)(&As[0][off]);
                al[mi] = *(const short8*)(&As[1][off]);
            }
            #pragma unroll
            for (int ni = 0; ni < 4; ++ni) {
                int n = wn + ni * 16 + l15;
                int off = n * 64 + ((s ^ (n & 7)) * 8);
                bh[ni] = *(const short8*)(&Bs[0][off]);
                bl[ni] = *(const short8*)(&Bs[1][off]);
            }
            #pragma unroll
            for (int mi = 0; mi < 4; ++mi)
                #pragma unroll
                for (int ni = 0; ni < 4; ++ni) {
                    acc[mi][ni] = __builtin_amdgcn_mfma_f32_16x16x32_bf16(
                        ah[mi], bh[ni], acc[mi][ni], 0, 0, 0);
                    acc[mi][ni] = __builtin_amdgcn_mfma_f32_16x16x32_bf16(
                        ah[mi], bl[ni], acc[mi][ni], 0, 0, 0);
                    acc[mi][ni] = __builtin_amdgcn_mfma_f32_16x16x32_bf16(
                        al[mi], bh[ni], acc[mi][ni], 0, 0, 0);
                }
        }
        __syncthreads();
    }

    #pragma unroll
    for (int mi = 0; mi < 4; ++mi) {
        #pragma unroll
        for (int r = 0; r < 4; ++r) {
            int row = bm + wm + mi * 16 + lhi * 4 + r;
            bool msk = true;
            if (DO_MASK) msk = (tokens[row] != 0);
            #pragma unroll
            for (int ni = 0; ni < 4; ++ni) {
                int col = bn + wn + ni * 16 + l15;
                float v = acc[mi][ni][r] + bias[n0 + col];
                if (DO_MASK && !msk) v = ((n0 + col) == 0) ? 1.f : 0.f;
                C[(size_t)row * ldc + n0 + col] = v;
            }
        }
    }
}

// ---------------------------------------------------------------------------
// Relayout Wh [1024][4096] fp32 -> WhL[bx][k4][col] float4 so step-kernel
// reads are 256B-contiguous per wave (L2-hot, 2MB per XCD).
// ---------------------------------------------------------------------------
__global__ __launch_bounds__(256)
void wrelay_k(const float* __restrict__ Wh, float* __restrict__ WhL)
{
    int i  = blockIdx.x * 256 + threadIdx.x;   // float4 id; 1024*1024 total
    int kk = i >> 10, j4 = i & 1023;
    float4 v = ((const float4*)Wh)[(size_t)i];
    int g  = j4 >> 8;                          // gate
    int bx = j4 & 255;                         // unit quad
    int k4 = kk >> 2, e = kk & 3;
    float* dst = WhL + ((((size_t)(bx * 256 + k4)) * 16 + g * 4) * 4 + e);
    dst[0] = v.x; dst[4] = v.y; dst[8] = v.z; dst[12] = v.w;
}

// ---------------------------------------------------------------------------
// One LSTM timestep, no LDS: Wh read straight from L2 (contiguous 256B per
// wave-instr via WhL layout), h_prev broadcast reads, 4-acc ILP, no barrier.
// ---------------------------------------------------------------------------
__global__ __launch_bounds__(256)
void lstm_step3_k(const float* __restrict__ xz,   // [B*T, 4H]
                  const float4* __restrict__ WhL4,
                  float* __restrict__ hseq,       // [B*T, H]
                  float* __restrict__ cs,         // [B, H]
                  const int* __restrict__ tokens, int t)
{
    const int tid = threadIdx.x, bx = blockIdx.x;
    const int b   = tid >> 4;
    const int col = tid & 15;                  // g*4 + uu
    const int g   = col >> 2;
    const int u   = bx * 4 + (col & 3);
    const int j   = g * H_ + u;

    float a0 = 0.f, a1 = 0.f, a2 = 0.f, a3 = 0.f, hp_ = 0.f;
    if (t > 0) {
        const float4* w = WhL4 + (size_t)bx * 4096 + col;
        const float4* h = (const float4*)(hseq + ((size_t)(b * T_ + t - 1)) * H_);
        #pragma unroll 16
        for (int k4 = 0; k4 < 256; ++k4) {
            float4 w4 = w[(size_t)k4 * 16];
            float4 h4 = h[k4];
            a0 += h4.x * w4.x; a1 += h4.y * w4.y;
            a2 += h4.z * w4.z; a3 += h4.w * w4.w;
        }
        hp_ = hseq[((size_t)(b * T_ + t - 1)) * H_ + u];
    }
    float z = (a0 + a1) + (a2 + a3) + xz[((size_t)(b * T_ + t)) * (4 * H_) + j];

    const int lane = tid & 63;
    const int base = lane & 0x33;
    float zi = __shfl(z, base, 64);
    float zf = __shfl(z, base + 4, 64);
    float zg = __shfl(z, base + 8, 64);
    float zo = __shfl(z, base + 12, 64);

    if ((lane & 12) == 0) {                    // g==0 lanes
        float i_ = 1.f / (1.f + expf(-zi));
        float f_ = 1.f / (1.f + expf(-zf));
        float g_ = tanhf(zg);
        float o_ = 1.f / (1.f + expf(-zo));
        float c_old = (t > 0) ? cs[b * H_ + u] : 0.f;
        float c_new = f_ * c_old + i_ * g_;
        float h_new = o_ * tanhf(c_new);
        bool  m  = (tokens[b * T_ + t] != 0);
        float h2 = m ? h_new : hp_;
        float c2 = m ? c_new : c_old;
        cs[b * H_ + u] = c2;
        hseq[((size_t)(b * T_ + t)) * H_ + u] = h2;
    }
}

// ---------------------------------------------------------------------------
extern "C" void kernel_launch(void* const* d_in, const int* in_sizes, int n_in,
                              void* d_out, int out_size, void* d_ws, size_t ws_size,
                              hipStream_t stream)
{
    const int*   tokens = (const int*)d_in[0];
    const float* emb    = (const float*)d_in[1];
    const float* Wx0    = (const float*)d_in[2];
    const float* Wh0    = (const float*)d_in[3];
    const float* b0     = (const float*)d_in[4];
    const float* Wx1    = (const float*)d_in[5];
    const float* Wh1    = (const float*)d_in[6];
    const float* b1     = (const float*)d_in[7];
    const float* Wout   = (const float*)d_in[8];
    const float* bout   = (const float*)d_in[9];
    float* out = (float*)d_out;

    // d_ws: bf16 planes (~82 MB; round-0 proved >=109 MB usable)
    unsigned short* wsu = (unsigned short*)d_ws;
    const size_t BPL = (size_t)16000 * 1024;          // B-plane slot (shorts)
    unsigned short* Bh  = wsu;
    unsigned short* Bl  = wsu + BPL;
    unsigned short* Ahp = wsu + 2 * BPL;
    unsigned short* Alp = Ahp + (size_t)4096 * 1024;

    // d_out head used as fp32 scratch; all dead before GEMM3 writes logits.
    float* f   = (float*)d_out;
    float* xz  = f;                                   // 16.78M floats
    float* WhL = xz + (size_t)4096 * 4096;            // 4.19M
    float* h0  = WhL + (size_t)1024 * 4096;           // 4.19M
    float* h1  = h0 + (size_t)4096 * 1024;            // 4.19M
    float* cst = h1 + (size_t)4096 * 1024;            // 16K

    dim3 blk(256);

    // ---- layer 0 input projection ----
    gather_cvt_k<<<2048, blk, 0, stream>>>(tokens, emb, Ahp, Alp);
    twz_k<<<dim3(128, 16), blk, 0, stream>>>(Wx0, Bh, Bl, 512, 4096, 0);
    mgemm_k<0><<<dim3(32, 32), blk, 0, stream>>>(Ahp, Alp, Bh, Bl, b0, xz,
                                                 nullptr, 512, 4096, 0);
    // ---- layer 0 recurrence ----
    wrelay_k<<<4096, blk, 0, stream>>>(Wh0, WhL);
    for (int t = 0; t < T_; ++t)
        lstm_step3_k<<<256, blk, 0, stream>>>(xz, (const float4*)WhL, h0, cst,
                                              tokens, t);
    // ---- layer 1 input projection ----
    cvt_k<<<4096, blk, 0, stream>>>(h0, Ahp, Alp);
    twz_k<<<dim3(128, 32), blk, 0, stream>>>(Wx1, Bh, Bl, 1024, 4096, 0);
    mgemm_k<0><<<dim3(32, 32), blk, 0, stream>>>(Ahp, Alp, Bh, Bl, b1, xz,
                                                 nullptr, 1024, 4096, 0);
    // ---- layer 1 recurrence ----
    wrelay_k<<<4096, blk, 0, stream>>>(Wh1, WhL);
    for (int t = 0; t < T_; ++t)
        lstm_step3_k<<<256, blk, 0, stream>>>(xz, (const float4*)WhL, h1, cst,
                                              tokens, t);
    // ---- vocab projection in two N-halves (bounds ws usage) ----
    cvt_k<<<4096, blk, 0, stream>>>(h1, Ahp, Alp);
    twz_k<<<dim3(500, 32), blk, 0, stream>>>(Wout, Bh, Bl, 1024, 32000, 0);
    mgemm_k<1><<<dim3(125, 32), blk, 0, stream>>>(Ahp, Alp, Bh, Bl, bout, out,
                                                  tokens, 1024, 32000, 0);
    twz_k<<<dim3(500, 32), blk, 0, stream>>>(Wout, Bh, Bl, 1024, 32000, 16000);
    mgemm_k<1><<<dim3(125, 32), blk, 0, stream>>>(Ahp, Alp, Bh, Bl, bout, out,
                                                  tokens, 1024, 32000, 16000);
}

// Round 5
// 7206.077 us; speedup vs baseline: 2.3052x; 2.3052x over previous
//
#include <hip/hip_runtime.h>

#define B_ 16
#define T_ 256
#define E_ 512
#define H_ 1024
#define V_ 32000

typedef float f32x4 __attribute__((ext_vector_type(4)));
typedef short short8 __attribute__((ext_vector_type(8)));

typedef __attribute__((address_space(1))) const void gas_t;
typedef __attribute__((address_space(3))) void las_t;

__device__ __forceinline__ unsigned short f2bf(float x) {
    unsigned int u = __float_as_uint(x);
    u += 0x7FFF + ((u >> 16) & 1);            // RTNE
    return (unsigned short)(u >> 16);
}
__device__ __forceinline__ float bf2f(unsigned short b) {
    return __uint_as_float(((unsigned int)b) << 16);
}

// ---------------------------------------------------------------------------
// Embedding gather fused with bf16 hi/lo split: emb[tokens] -> Ah/Al [4096,512]
// ---------------------------------------------------------------------------
__global__ __launch_bounds__(256)
void gather_cvt_k(const int* __restrict__ tokens, const float* __restrict__ emb,
                  unsigned short* __restrict__ Ah, unsigned short* __restrict__ Al)
{
    int i  = blockIdx.x * 256 + threadIdx.x;   // float4 id; 4096*128 total
    int bt = i >> 7;
    int e4 = i & 127;
    float4 v = ((const float4*)(emb + (size_t)tokens[bt] * E_))[e4];
    ushort4 h, l;
    h.x = f2bf(v.x); l.x = f2bf(v.x - bf2f(h.x));
    h.y = f2bf(v.y); l.y = f2bf(v.y - bf2f(h.y));
    h.z = f2bf(v.z); l.z = f2bf(v.z - bf2f(h.z));
    h.w = f2bf(v.w); l.w = f2bf(v.w - bf2f(h.w));
    ((ushort4*)Ah)[i] = h;
    ((ushort4*)Al)[i] = l;
}

// ---------------------------------------------------------------------------
// fp32 -> bf16 hi/lo split (A activations, row-major, no transpose)
// ---------------------------------------------------------------------------
__global__ __launch_bounds__(256)
void cvt_k(const float* __restrict__ A, unsigned short* __restrict__ Ah,
           unsigned short* __restrict__ Al)
{
    int i = blockIdx.x * 256 + threadIdx.x;    // float4 id
    float4 v = ((const float4*)A)[i];
    ushort4 h, l;
    h.x = f2bf(v.x); l.x = f2bf(v.x - bf2f(h.x));
    h.y = f2bf(v.y); l.y = f2bf(v.y - bf2f(h.y));
    h.z = f2bf(v.z); l.z = f2bf(v.z - bf2f(h.z));
    h.w = f2bf(v.w); l.w = f2bf(v.w - bf2f(h.w));
    ((ushort4*)Ah)[i] = h;
    ((ushort4*)Al)[i] = l;
}

// ---------------------------------------------------------------------------
// Weight transpose + split: W fp32 [K][Nfull], col slice [n0, n0+NS) ->
// Bh/Bl bf16 [NS][K]. 32x32 LDS tiles, +1 pad, coalesced both sides.
// ---------------------------------------------------------------------------
__global__ __launch_bounds__(256)
void twz_k(const float* __restrict__ W, unsigned short* __restrict__ Bh,
           unsigned short* __restrict__ Bl, int Kd, int Nfull, int n0)
{
    __shared__ float tile[32][33];
    int t  = threadIdx.x;
    int tx = t & 31, ty = t >> 5;              // ty 0..7
    int nb = blockIdx.x * 32, kb = blockIdx.y * 32;
    #pragma unroll
    for (int i = 0; i < 4; ++i)
        tile[ty + i * 8][tx] = W[(size_t)(kb + ty + i * 8) * Nfull + n0 + nb + tx];
    __syncthreads();
    #pragma unroll
    for (int i = 0; i < 4; ++i) {
        float v = tile[tx][ty + i * 8];
        unsigned short h = f2bf(v), l = f2bf(v - bf2f(h));
        size_t o = (size_t)(nb + ty + i * 8) * Kd + kb + tx;
        Bh[o] = h; Bl[o] = l;
    }
}

// ---------------------------------------------------------------------------
// Split-bf16 3-pass MFMA GEMM v2: staging via global_load_lds width 16.
// Wave w stages plane w (0=Ah 1=Al 2=Bh 3=Bl): LDS dest linear, global
// source pre-swizzled with scol = (lane&7)^(lane>>3) so LDS[row][s'] =
// glob[row][s'^(row&7)] (involution of the read-side XOR). Frag reads and
// C/D layout identical to the round-4-verified kernel.
// ---------------------------------------------------------------------------
template<int DO_MASK>
__global__ __launch_bounds__(256)
void mgemm_k(const unsigned short* __restrict__ Ah, const unsigned short* __restrict__ Al,
             const unsigned short* __restrict__ Bh, const unsigned short* __restrict__ Bl,
             const float* __restrict__ bias, float* __restrict__ C,
             const int* __restrict__ tokens, int K, int ldc, int n0)
{
    __shared__ unsigned short LDSS[4][128 * 64];   // 64 KB: Ah,Al,Bh,Bl planes

    const int tid  = threadIdx.x;
    const int bm   = blockIdx.y * 128;
    const int bn   = blockIdx.x * 128;
    const int w    = tid >> 6, lane = tid & 63;
    const int wm   = (w >> 1) * 64, wn = (w & 1) * 64;
    const int l15  = lane & 15, lhi = lane >> 4;

    // wave w's staging plane
    const unsigned short* gp = (w == 0) ? Ah : (w == 1) ? Al : (w == 2) ? Bh : Bl;
    const int rb = (w < 2) ? bm : bn;
    const int srow = lane >> 3;                    // row within 8-row chunk
    const int scol = (lane & 7) ^ srow;            // pre-swizzled 16B slot
    unsigned short* lbase = &LDSS[w][0];

    f32x4 acc[4][4];
    #pragma unroll
    for (int mi = 0; mi < 4; ++mi)
        #pragma unroll
        for (int ni = 0; ni < 4; ++ni) {
            f32x4 z = {0.f, 0.f, 0.f, 0.f};
            acc[mi][ni] = z;
        }

    for (int kt = 0; kt < K; kt += 64) {
        #pragma unroll
        for (int c = 0; c < 16; ++c) {
            const unsigned short* src =
                gp + (size_t)(rb + c * 8 + srow) * K + kt + scol * 8;
            __builtin_amdgcn_global_load_lds((gas_t*)src,
                                             (las_t*)(lbase + c * 512), 16, 0, 0);
        }
        __syncthreads();                            // drains vmcnt, LDS ready
        #pragma unroll
        for (int ks = 0; ks < 2; ++ks) {
            short8 ah[4], al[4], bh[4], bl[4];
            const int s = ks * 4 + lhi;
            #pragma unroll
            for (int mi = 0; mi < 4; ++mi) {
                int m = wm + mi * 16 + l15;
                int off = m * 64 + ((s ^ (m & 7)) * 8);
                ah[mi] = *(const short8*)(&LDSS[0][off]);
                al[mi] = *(const short8*)(&LDSS[1][off]);
            }
            #pragma unroll
            for (int ni = 0; ni < 4; ++ni) {
                int n = wn + ni * 16 + l15;
                int off = n * 64 + ((s ^ (n & 7)) * 8);
                bh[ni] = *(const short8*)(&LDSS[2][off]);
                bl[ni] = *(const short8*)(&LDSS[3][off]);
            }
            #pragma unroll
            for (int mi = 0; mi < 4; ++mi)
                #pragma unroll
                for (int ni = 0; ni < 4; ++ni) {
                    acc[mi][ni] = __builtin_amdgcn_mfma_f32_16x16x32_bf16(
                        ah[mi], bh[ni], acc[mi][ni], 0, 0, 0);
                    acc[mi][ni] = __builtin_amdgcn_mfma_f32_16x16x32_bf16(
                        ah[mi], bl[ni], acc[mi][ni], 0, 0, 0);
                    acc[mi][ni] = __builtin_amdgcn_mfma_f32_16x16x32_bf16(
                        al[mi], bh[ni], acc[mi][ni], 0, 0, 0);
                }
        }
        __syncthreads();                            // done reading before refill
    }

    #pragma unroll
    for (int mi = 0; mi < 4; ++mi) {
        #pragma unroll
        for (int r = 0; r < 4; ++r) {
            int row = bm + wm + mi * 16 + lhi * 4 + r;
            bool msk = true;
            if (DO_MASK) msk = (tokens[row] != 0);
            #pragma unroll
            for (int ni = 0; ni < 4; ++ni) {
                int col = bn + wn + ni * 16 + l15;
                float v = acc[mi][ni][r] + bias[n0 + col];
                if (DO_MASK && !msk) v = ((n0 + col) == 0) ? 1.f : 0.f;
                C[(size_t)row * ldc + n0 + col] = v;
            }
        }
    }
}

// ---------------------------------------------------------------------------
// Pre-swizzle Wh [1024][4096] into per-block images WhS[bx][col][k4^(col&7)]
// (float4 packs k). Per-step staging becomes a LINEAR 64 KB copy; LDS reads
// are 2-way-bank-aliased (free).
// ---------------------------------------------------------------------------
__global__ __launch_bounds__(256)
void wswz_k(const float* __restrict__ Wh, float* __restrict__ WhS)
{
    int i  = blockIdx.x * 256 + threadIdx.x;   // 0 .. 1048575
    int k  = i >> 10;                          // 0..1023
    int j4 = i & 1023;                         // float4 along j
    float4 v = *(const float4*)&Wh[(size_t)k * (4 * H_) + j4 * 4];
    int k4 = k >> 2, e = k & 3;
    float vv[4] = {v.x, v.y, v.z, v.w};
    #pragma unroll
    for (int q = 0; q < 4; ++q) {
        int j   = j4 * 4 + q;
        int u   = j & (H_ - 1);
        int g   = j >> 10;
        int bx  = u >> 2;
        int col = g * 4 + (u & 3);
        int dst = ((bx << 12) + (col << 8) + (k4 ^ (col & 7))) * 4 + e;
        WhS[dst] = vv[q];
    }
}

// ---------------------------------------------------------------------------
// One LSTM timestep, v4: 512 threads/block (2 waves/SIMD at 1 block/CU).
// thread = (b = tid>>5, khalf = (tid>>4)&1, col = tid&15); each computes a
// half-dot (512 k), combined via __shfl_xor(16) with its in-wave partner.
// Wh slice from LDS (staged linear from pre-swizzled WhS), h_prev broadcast
// from L1/L2. Gates combined via __shfl; sync = kernel boundary.
// ---------------------------------------------------------------------------
__global__ __launch_bounds__(512)
void lstm_step4_k(const float* __restrict__ xz,   // [B*T, 4H] rows bt=b*T+t
                  const float4* __restrict__ WhS4,
                  float* __restrict__ hseq,       // [B*T, H]
                  float* __restrict__ cs,         // [B, H]
                  const int* __restrict__ tokens, int t)
{
    __shared__ float4 Ws4[4096];                  // exactly 64 KB
    const int tid = threadIdx.x, bx = blockIdx.x;

    const int b     = tid >> 5;
    const int khalf = (tid >> 4) & 1;
    const int col   = tid & 15;                   // g*4 + uu
    const int g     = col >> 2;
    const int u     = bx * 4 + (col & 3);
    const int j     = g * H_ + u;

    float a0 = 0.f, a1 = 0.f, a2 = 0.f, a3 = 0.f;
    if (t > 0) {
        const float4* src = WhS4 + (size_t)bx * 4096;
        #pragma unroll 8
        for (int i = tid; i < 4096; i += 512) Ws4[i] = src[i];
        __syncthreads();

        const float4* hp =
            (const float4*)(hseq + ((size_t)(b * T_ + t - 1)) * H_) + khalf * 128;
        const float4* wp = Ws4 + col * 256 + khalf * 128;
        const int sw = col & 7;
        #pragma unroll 8
        for (int kk = 0; kk < 128; ++kk) {
            float4 h4 = hp[kk];
            float4 w4 = wp[kk ^ sw];
            a0 += h4.x * w4.x; a1 += h4.y * w4.y;
            a2 += h4.z * w4.z; a3 += h4.w * w4.w;
        }
    }
    float zp = (a0 + a1) + (a2 + a3);
    zp += __shfl_xor(zp, 16, 64);                 // merge k-halves (in-wave)
    float z = zp + xz[((size_t)(b * T_ + t)) * (4 * H_) + j];

    const int lane = tid & 63;
    const int base = lane & 0x23;                 // khalf=0, g=0, same (b,uu)
    float zi = __shfl(z, base, 64);
    float zf = __shfl(z, base + 4, 64);
    float zg = __shfl(z, base + 8, 64);
    float zo = __shfl(z, base + 12, 64);

    if ((lane & 0x1C) == 0) {                     // khalf==0 && g==0 lanes
        float i_ = 1.f / (1.f + expf(-zi));
        float f_ = 1.f / (1.f + expf(-zf));
        float g_ = tanhf(zg);
        float o_ = 1.f / (1.f + expf(-zo));
        float c_old = (t > 0) ? cs[b * H_ + u] : 0.f;
        float c_new = f_ * c_old + i_ * g_;
        float h_new = o_ * tanhf(c_new);
        bool  m  = (tokens[b * T_ + t] != 0);
        float hp_ = (t > 0) ? hseq[((size_t)(b * T_ + t - 1)) * H_ + u] : 0.f;
        float h2 = m ? h_new : hp_;
        float c2 = m ? c_new : c_old;
        cs[b * H_ + u] = c2;
        hseq[((size_t)(b * T_ + t)) * H_ + u] = h2;
    }
}

// ---------------------------------------------------------------------------
extern "C" void kernel_launch(void* const* d_in, const int* in_sizes, int n_in,
                              void* d_out, int out_size, void* d_ws, size_t ws_size,
                              hipStream_t stream)
{
    const int*   tokens = (const int*)d_in[0];
    const float* emb    = (const float*)d_in[1];
    const float* Wx0    = (const float*)d_in[2];
    const float* Wh0    = (const float*)d_in[3];
    const float* b0     = (const float*)d_in[4];
    const float* Wx1    = (const float*)d_in[5];
    const float* Wh1    = (const float*)d_in[6];
    const float* b1     = (const float*)d_in[7];
    const float* Wout   = (const float*)d_in[8];
    const float* bout   = (const float*)d_in[9];
    float* out = (float*)d_out;

    // d_ws: bf16 planes (~82 MB)
    unsigned short* wsu = (unsigned short*)d_ws;
    const size_t BPL = (size_t)16000 * 1024;          // B-plane slot (shorts)
    unsigned short* Bh  = wsu;
    unsigned short* Bl  = wsu + BPL;
    unsigned short* Ahp = wsu + 2 * BPL;
    unsigned short* Alp = Ahp + (size_t)4096 * 1024;

    // d_out head used as fp32 scratch; all dead before GEMM3 writes logits.
    float* f   = (float*)d_out;
    float* xz  = f;                                   // 16.78M floats
    float* WhS = xz + (size_t)4096 * 4096;            // 4.19M
    float* h0  = WhS + (size_t)1024 * 4096;           // 4.19M
    float* h1  = h0 + (size_t)4096 * 1024;            // 4.19M
    float* cst = h1 + (size_t)4096 * 1024;            // 16K

    dim3 blk(256);

    // ---- layer 0 input projection ----
    gather_cvt_k<<<2048, blk, 0, stream>>>(tokens, emb, Ahp, Alp);
    twz_k<<<dim3(128, 16), blk, 0, stream>>>(Wx0, Bh, Bl, 512, 4096, 0);
    mgemm_k<0><<<dim3(32, 32), blk, 0, stream>>>(Ahp, Alp, Bh, Bl, b0, xz,
                                                 nullptr, 512, 4096, 0);
    // ---- layer 0 recurrence ----
    wswz_k<<<4096, blk, 0, stream>>>(Wh0, WhS);
    for (int t = 0; t < T_; ++t)
        lstm_step4_k<<<256, dim3(512), 0, stream>>>(xz, (const float4*)WhS, h0,
                                                    cst, tokens, t);
    // ---- layer 1 input projection ----
    cvt_k<<<4096, blk, 0, stream>>>(h0, Ahp, Alp);
    twz_k<<<dim3(128, 32), blk, 0, stream>>>(Wx1, Bh, Bl, 1024, 4096, 0);
    mgemm_k<0><<<dim3(32, 32), blk, 0, stream>>>(Ahp, Alp, Bh, Bl, b1, xz,
                                                 nullptr, 1024, 4096, 0);
    // ---- layer 1 recurrence ----
    wswz_k<<<4096, blk, 0, stream>>>(Wh1, WhS);
    for (int t = 0; t < T_; ++t)
        lstm_step4_k<<<256, dim3(512), 0, stream>>>(xz, (const float4*)WhS, h1,
                                                    cst, tokens, t);
    // ---- vocab projection in two N-halves (bounds ws usage) ----
    cvt_k<<<4096, blk, 0, stream>>>(h1, Ahp, Alp);
    twz_k<<<dim3(500, 32), blk, 0, stream>>>(Wout, Bh, Bl, 1024, 32000, 0);
    mgemm_k<1><<<dim3(125, 32), blk, 0, stream>>>(Ahp, Alp, Bh, Bl, bout, out,
                                                  tokens, 1024, 32000, 0);
    twz_k<<<dim3(500, 32), blk, 0, stream>>>(Wout, Bh, Bl, 1024, 32000, 16000);
    mgemm_k<1><<<dim3(125, 32), blk, 0, stream>>>(Ahp, Alp, Bh, Bl, bout, out,
                                                  tokens, 1024, 32000, 16000);
}

// Round 6
// 5428.654 us; speedup vs baseline: 3.0600x; 1.3274x over previous
//
#include <hip/hip_runtime.h>

#define B_ 16
#define T_ 256
#define E_ 512
#define H_ 1024
#define V_ 32000

typedef float f32x4 __attribute__((ext_vector_type(4)));
typedef short short8 __attribute__((ext_vector_type(8)));

typedef __attribute__((address_space(1))) const void gas_t;
typedef __attribute__((address_space(3))) void las_t;

__device__ __forceinline__ unsigned short f2bf(float x) {
    unsigned int u = __float_as_uint(x);
    u += 0x7FFF + ((u >> 16) & 1);            // RTNE
    return (unsigned short)(u >> 16);
}
__device__ __forceinline__ float bf2f(unsigned short b) {
    return __uint_as_float(((unsigned int)b) << 16);
}

// ---------------------------------------------------------------------------
// Embedding gather fused with bf16 hi/lo split: emb[tokens] -> Ah/Al [4096,512]
// ---------------------------------------------------------------------------
__global__ __launch_bounds__(256)
void gather_cvt_k(const int* __restrict__ tokens, const float* __restrict__ emb,
                  unsigned short* __restrict__ Ah, unsigned short* __restrict__ Al)
{
    int i  = blockIdx.x * 256 + threadIdx.x;   // float4 id; 4096*128 total
    int bt = i >> 7;
    int e4 = i & 127;
    float4 v = ((const float4*)(emb + (size_t)tokens[bt] * E_))[e4];
    ushort4 h, l;
    h.x = f2bf(v.x); l.x = f2bf(v.x - bf2f(h.x));
    h.y = f2bf(v.y); l.y = f2bf(v.y - bf2f(h.y));
    h.z = f2bf(v.z); l.z = f2bf(v.z - bf2f(h.z));
    h.w = f2bf(v.w); l.w = f2bf(v.w - bf2f(h.w));
    ((ushort4*)Ah)[i] = h;
    ((ushort4*)Al)[i] = l;
}

// ---------------------------------------------------------------------------
// fp32 -> bf16 hi/lo split (A activations, row-major, no transpose)
// ---------------------------------------------------------------------------
__global__ __launch_bounds__(256)
void cvt_k(const float* __restrict__ A, unsigned short* __restrict__ Ah,
           unsigned short* __restrict__ Al)
{
    int i = blockIdx.x * 256 + threadIdx.x;    // float4 id
    float4 v = ((const float4*)A)[i];
    ushort4 h, l;
    h.x = f2bf(v.x); l.x = f2bf(v.x - bf2f(h.x));
    h.y = f2bf(v.y); l.y = f2bf(v.y - bf2f(h.y));
    h.z = f2bf(v.z); l.z = f2bf(v.z - bf2f(h.z));
    h.w = f2bf(v.w); l.w = f2bf(v.w - bf2f(h.w));
    ((ushort4*)Ah)[i] = h;
    ((ushort4*)Al)[i] = l;
}

// ---------------------------------------------------------------------------
// Weight transpose + split: W fp32 [K][Nfull], col slice [n0, n0+NS) ->
// Bh/Bl bf16 [NS][K]. 32x32 LDS tiles, +1 pad, coalesced both sides.
// ---------------------------------------------------------------------------
__global__ __launch_bounds__(256)
void twz_k(const float* __restrict__ W, unsigned short* __restrict__ Bh,
           unsigned short* __restrict__ Bl, int Kd, int Nfull, int n0)
{
    __shared__ float tile[32][33];
    int t  = threadIdx.x;
    int tx = t & 31, ty = t >> 5;              // ty 0..7
    int nb = blockIdx.x * 32, kb = blockIdx.y * 32;
    #pragma unroll
    for (int i = 0; i < 4; ++i)
        tile[ty + i * 8][tx] = W[(size_t)(kb + ty + i * 8) * Nfull + n0 + nb + tx];
    __syncthreads();
    #pragma unroll
    for (int i = 0; i < 4; ++i) {
        float v = tile[tx][ty + i * 8];
        unsigned short h = f2bf(v), l = f2bf(v - bf2f(h));
        size_t o = (size_t)(nb + ty + i * 8) * Kd + kb + tx;
        Bh[o] = h; Bl[o] = l;
    }
}

// ---------------------------------------------------------------------------
// Split-bf16 3-pass MFMA GEMM (round-5-verified, unchanged): staging via
// global_load_lds width 16, pre-swizzled source, XOR-swizzled LDS reads.
// ---------------------------------------------------------------------------
template<int DO_MASK>
__global__ __launch_bounds__(256)
void mgemm_k(const unsigned short* __restrict__ Ah, const unsigned short* __restrict__ Al,
             const unsigned short* __restrict__ Bh, const unsigned short* __restrict__ Bl,
             const float* __restrict__ bias, float* __restrict__ C,
             const int* __restrict__ tokens, int K, int ldc, int n0)
{
    __shared__ unsigned short LDSS[4][128 * 64];   // 64 KB: Ah,Al,Bh,Bl planes

    const int tid  = threadIdx.x;
    const int bm   = blockIdx.y * 128;
    const int bn   = blockIdx.x * 128;
    const int w    = tid >> 6, lane = tid & 63;
    const int wm   = (w >> 1) * 64, wn = (w & 1) * 64;
    const int l15  = lane & 15, lhi = lane >> 4;

    const unsigned short* gp = (w == 0) ? Ah : (w == 1) ? Al : (w == 2) ? Bh : Bl;
    const int rb = (w < 2) ? bm : bn;
    const int srow = lane >> 3;
    const int scol = (lane & 7) ^ srow;
    unsigned short* lbase = &LDSS[w][0];

    f32x4 acc[4][4];
    #pragma unroll
    for (int mi = 0; mi < 4; ++mi)
        #pragma unroll
        for (int ni = 0; ni < 4; ++ni) {
            f32x4 z = {0.f, 0.f, 0.f, 0.f};
            acc[mi][ni] = z;
        }

    for (int kt = 0; kt < K; kt += 64) {
        #pragma unroll
        for (int c = 0; c < 16; ++c) {
            const unsigned short* src =
                gp + (size_t)(rb + c * 8 + srow) * K + kt + scol * 8;
            __builtin_amdgcn_global_load_lds((gas_t*)src,
                                             (las_t*)(lbase + c * 512), 16, 0, 0);
        }
        __syncthreads();
        #pragma unroll
        for (int ks = 0; ks < 2; ++ks) {
            short8 ah[4], al[4], bh[4], bl[4];
            const int s = ks * 4 + lhi;
            #pragma unroll
            for (int mi = 0; mi < 4; ++mi) {
                int m = wm + mi * 16 + l15;
                int off = m * 64 + ((s ^ (m & 7)) * 8);
                ah[mi] = *(const short8*)(&LDSS[0][off]);
                al[mi] = *(const short8*)(&LDSS[1][off]);
            }
            #pragma unroll
            for (int ni = 0; ni < 4; ++ni) {
                int n = wn + ni * 16 + l15;
                int off = n * 64 + ((s ^ (n & 7)) * 8);
                bh[ni] = *(const short8*)(&LDSS[2][off]);
                bl[ni] = *(const short8*)(&LDSS[3][off]);
            }
            #pragma unroll
            for (int mi = 0; mi < 4; ++mi)
                #pragma unroll
                for (int ni = 0; ni < 4; ++ni) {
                    acc[mi][ni] = __builtin_amdgcn_mfma_f32_16x16x32_bf16(
                        ah[mi], bh[ni], acc[mi][ni], 0, 0, 0);
                    acc[mi][ni] = __builtin_amdgcn_mfma_f32_16x16x32_bf16(
                        ah[mi], bl[ni], acc[mi][ni], 0, 0, 0);
                    acc[mi][ni] = __builtin_amdgcn_mfma_f32_16x16x32_bf16(
                        al[mi], bh[ni], acc[mi][ni], 0, 0, 0);
                }
        }
        __syncthreads();
    }

    #pragma unroll
    for (int mi = 0; mi < 4; ++mi) {
        #pragma unroll
        for (int r = 0; r < 4; ++r) {
            int row = bm + wm + mi * 16 + lhi * 4 + r;
            bool msk = true;
            if (DO_MASK) msk = (tokens[row] != 0);
            #pragma unroll
            for (int ni = 0; ni < 4; ++ni) {
                int col = bn + wn + ni * 16 + l15;
                float v = acc[mi][ni][r] + bias[n0 + col];
                if (DO_MASK && !msk) v = ((n0 + col) == 0) ? 1.f : 0.f;
                C[(size_t)row * ldc + n0 + col] = v;
            }
        }
    }
}

// ---------------------------------------------------------------------------
// Wh [1024][4096] fp32 -> register-fragment image WhF (bf16 hi/lo B-frags).
// Block bx (of 64) owns cols j = ct*1024 + bx*16 + (l&15), ct=gate 0..3;
// wave w owns k in [w*128, w*128+128). Frag (ct,kf,plane,lane) stored so the
// persistent kernel's load is lane-consecutive uint4 (perfect coalescing).
// Also resets the grid-barrier counter for the following persistent launch.
// ---------------------------------------------------------------------------
__global__ __launch_bounds__(256)
void wprep_k(const float* __restrict__ Wh, uint4* __restrict__ WhF,
             unsigned* __restrict__ bar)
{
    int flat = blockIdx.x * 256 + threadIdx.x;      // 0 .. 524287
    if (flat == 0) *bar = 0;
    int l  = flat & 63;
    int kf = (flat >> 6) & 3;
    int ct = (flat >> 8) & 3;
    int w  = (flat >> 10) & 7;
    int bx = flat >> 13;                            // 0..63
    int k0  = w * 128 + kf * 32 + 8 * (l >> 4);
    int col = ct * H_ + bx * 16 + (l & 15);
    unsigned short hi[8], lo[8];
    #pragma unroll
    for (int j = 0; j < 8; ++j) {
        float v = Wh[(size_t)(k0 + j) * (4 * H_) + col];
        hi[j] = f2bf(v); lo[j] = f2bf(v - bf2f(hi[j]));
    }
    size_t base = ((((size_t)bx * 8 + w) * 4 + ct) * 4 + kf) * 2;
    WhF[(base + 0) * 64 + l] = *(uint4*)hi;
    WhF[(base + 1) * 64 + l] = *(uint4*)lo;
}

// ---------------------------------------------------------------------------
// Persistent MFMA LSTM layer. 64 blocks x 512 threads (cooperative).
// Wave w keeps its 128-k slice of Wh in 128 VGPRs (split-bf16 hi/lo B-frags).
// Per step: gather h[t-1] A-frags via agent-scope (MALL-coherent) loads,
// 48 MFMAs, cross-wave K-reduce through LDS (lane-consecutive, conflict-
// free), wave-0 in-lane gate math (all 4 gates of a (b,u) in one lane; c,h
// carried in registers), agent-scope h stores, relaxed-atomic counter
// barrier (no L2 flush; xz/tokens stay cached).
// ---------------------------------------------------------------------------
__global__ __launch_bounds__(512, 2)
void lstm_pers_k(const float* __restrict__ xz,   // [B*T][4H]
                 const uint4* __restrict__ WhF,
                 float* __restrict__ hseq,       // [B*T][H]
                 const int* __restrict__ tokens,
                 unsigned* __restrict__ bar)
{
    __shared__ f32x4 Rs[32 * 64];                 // 32 KB: [(ct*8+w)*64 + l]

    const int tid = threadIdx.x;
    const int bx  = blockIdx.x;                   // 0..63
    const int w   = tid >> 6;
    const int l   = tid & 63;
    const int l15 = l & 15, lhi = l >> 4;

    // one-time load of register-resident Wh fragments (coalesced)
    short8 Bhi[4][4], Blo[4][4];
    {
        const uint4* p = WhF + (((size_t)bx * 8 + w) * 32) * 64;
        #pragma unroll
        for (int ct = 0; ct < 4; ++ct)
            #pragma unroll
            for (int kf = 0; kf < 4; ++kf) {
                uint4 hv = p[((ct * 4 + kf) * 2 + 0) * 64 + l];
                uint4 lv = p[((ct * 4 + kf) * 2 + 1) * 64 + l];
                Bhi[ct][kf] = *(short8*)&hv;
                Blo[ct][kf] = *(short8*)&lv;
            }
    }

    f32x4 c4 = {0.f, 0.f, 0.f, 0.f};
    f32x4 h4 = {0.f, 0.f, 0.f, 0.f};
    const int u = bx * 16 + l15;                  // wave-0 gate-phase unit

    for (int t = 0; t < T_; ++t) {
        if (t > 0) {
            f32x4 acc0 = {0.f,0.f,0.f,0.f}, acc1 = acc0, acc2 = acc0, acc3 = acc0;
            const float* hrow = hseq + ((size_t)(l15 * T_ + t - 1)) * H_
                              + w * 128 + 8 * lhi;
            #pragma unroll
            for (int kf = 0; kf < 4; ++kf) {
                const unsigned long long* hp =
                    (const unsigned long long*)(hrow + kf * 32);
                float hv[8];
                #pragma unroll
                for (int q = 0; q < 4; ++q) {
                    unsigned long long d = __hip_atomic_load(hp + q,
                        __ATOMIC_RELAXED, __HIP_MEMORY_SCOPE_AGENT);
                    hv[q * 2]     = __uint_as_float((unsigned)d);
                    hv[q * 2 + 1] = __uint_as_float((unsigned)(d >> 32));
                }
                unsigned short hh[8], hl[8];
                #pragma unroll
                for (int j = 0; j < 8; ++j) {
                    hh[j] = f2bf(hv[j]);
                    hl[j] = f2bf(hv[j] - bf2f(hh[j]));
                }
                short8 ah = *(short8*)hh, al = *(short8*)hl;
                acc0 = __builtin_amdgcn_mfma_f32_16x16x32_bf16(ah, Bhi[0][kf], acc0, 0,0,0);
                acc0 = __builtin_amdgcn_mfma_f32_16x16x32_bf16(ah, Blo[0][kf], acc0, 0,0,0);
                acc0 = __builtin_amdgcn_mfma_f32_16x16x32_bf16(al, Bhi[0][kf], acc0, 0,0,0);
                acc1 = __builtin_amdgcn_mfma_f32_16x16x32_bf16(ah, Bhi[1][kf], acc1, 0,0,0);
                acc1 = __builtin_amdgcn_mfma_f32_16x16x32_bf16(ah, Blo[1][kf], acc1, 0,0,0);
                acc1 = __builtin_amdgcn_mfma_f32_16x16x32_bf16(al, Bhi[1][kf], acc1, 0,0,0);
                acc2 = __builtin_amdgcn_mfma_f32_16x16x32_bf16(ah, Bhi[2][kf], acc2, 0,0,0);
                acc2 = __builtin_amdgcn_mfma_f32_16x16x32_bf16(ah, Blo[2][kf], acc2, 0,0,0);
                acc2 = __builtin_amdgcn_mfma_f32_16x16x32_bf16(al, Bhi[2][kf], acc2, 0,0,0);
                acc3 = __builtin_amdgcn_mfma_f32_16x16x32_bf16(ah, Bhi[3][kf], acc3, 0,0,0);
                acc3 = __builtin_amdgcn_mfma_f32_16x16x32_bf16(ah, Blo[3][kf], acc3, 0,0,0);
                acc3 = __builtin_amdgcn_mfma_f32_16x16x32_bf16(al, Bhi[3][kf], acc3, 0,0,0);
            }
            Rs[(0 * 8 + w) * 64 + l] = acc0;
            Rs[(1 * 8 + w) * 64 + l] = acc1;
            Rs[(2 * 8 + w) * 64 + l] = acc2;
            Rs[(3 * 8 + w) * 64 + l] = acc3;
        }
        __syncthreads();

        if (w == 0) {
            f32x4 z4[4];
            #pragma unroll
            for (int ct = 0; ct < 4; ++ct) {
                f32x4 s = {0.f, 0.f, 0.f, 0.f};
                if (t > 0) {
                    #pragma unroll
                    for (int w2 = 0; w2 < 8; ++w2) {
                        f32x4 v = Rs[(ct * 8 + w2) * 64 + l];
                        s[0] += v[0]; s[1] += v[1]; s[2] += v[2]; s[3] += v[3];
                    }
                }
                z4[ct] = s;
            }
            #pragma unroll
            for (int r = 0; r < 4; ++r) {
                int b = lhi * 4 + r;
                size_t bt = (size_t)b * T_ + t;
                float zi = z4[0][r] + xz[bt * 4096 + 0 * H_ + u];
                float zf = z4[1][r] + xz[bt * 4096 + 1 * H_ + u];
                float zg = z4[2][r] + xz[bt * 4096 + 2 * H_ + u];
                float zo = z4[3][r] + xz[bt * 4096 + 3 * H_ + u];
                float i_ = 1.f / (1.f + expf(-zi));
                float f_ = 1.f / (1.f + expf(-zf));
                float g_ = tanhf(zg);
                float o_ = 1.f / (1.f + expf(-zo));
                float c_new = f_ * c4[r] + i_ * g_;
                float h_new = o_ * tanhf(c_new);
                bool  m  = (tokens[bt] != 0);
                float h2 = m ? h_new : h4[r];
                float c2 = m ? c_new : c4[r];
                c4[r] = c2;
                h4[r] = h2;
                __hip_atomic_store(&hseq[bt * H_ + u], h2,
                                   __ATOMIC_RELAXED, __HIP_MEMORY_SCOPE_AGENT);
            }
        }
        __syncthreads();                          // h stores drained (all threads)

        if (tid == 0) {
            __hip_atomic_fetch_add(bar, 1u, __ATOMIC_RELAXED,
                                   __HIP_MEMORY_SCOPE_AGENT);
            const unsigned tgt = 64u * (unsigned)(t + 1);
            while (__hip_atomic_load(bar, __ATOMIC_RELAXED,
                                     __HIP_MEMORY_SCOPE_AGENT) < tgt)
                __builtin_amdgcn_s_sleep(2);
        }
        __syncthreads();
    }
}

// ---------------------------------------------------------------------------
extern "C" void kernel_launch(void* const* d_in, const int* in_sizes, int n_in,
                              void* d_out, int out_size, void* d_ws, size_t ws_size,
                              hipStream_t stream)
{
    const int*   tokens = (const int*)d_in[0];
    const float* emb    = (const float*)d_in[1];
    const float* Wx0    = (const float*)d_in[2];
    const float* Wh0    = (const float*)d_in[3];
    const float* b0     = (const float*)d_in[4];
    const float* Wx1    = (const float*)d_in[5];
    const float* Wh1    = (const float*)d_in[6];
    const float* b1     = (const float*)d_in[7];
    const float* Wout   = (const float*)d_in[8];
    const float* bout   = (const float*)d_in[9];
    float* out = (float*)d_out;

    // d_ws: bf16 planes (~82.3 MB) + barrier counter
    unsigned short* wsu = (unsigned short*)d_ws;
    const size_t BPL = (size_t)16000 * 1024;          // B-plane slot (shorts)
    const size_t AP  = (size_t)4096 * 1024;           // A-plane slot (shorts)
    unsigned short* Bh  = wsu;
    unsigned short* Bl  = wsu + BPL;
    unsigned short* Ahp = wsu + 2 * BPL;
    unsigned short* Alp = Ahp + AP;
    unsigned* bar = (unsigned*)(wsu + 2 * BPL + 2 * AP);

    // d_out head used as fp32 scratch; all dead before final GEMM writes logits.
    float* f   = (float*)d_out;
    float* xz  = f;                                   // 16.78M floats
    float* WhF = xz + (size_t)4096 * 4096;            // 4.19M (frag image)
    float* h0  = WhF + (size_t)1024 * 4096;           // 4.19M
    float* h1  = h0 + (size_t)4096 * 1024;            // 4.19M

    dim3 blk(256);

    // ---- layer 0 input projection ----
    gather_cvt_k<<<2048, blk, 0, stream>>>(tokens, emb, Ahp, Alp);
    twz_k<<<dim3(128, 16), blk, 0, stream>>>(Wx0, Bh, Bl, 512, 4096, 0);
    mgemm_k<0><<<dim3(32, 32), blk, 0, stream>>>(Ahp, Alp, Bh, Bl, b0, xz,
                                                 nullptr, 512, 4096, 0);
    // ---- layer 0 recurrence (persistent) ----
    wprep_k<<<2048, blk, 0, stream>>>(Wh0, (uint4*)WhF, bar);
    {
        void* args[] = {(void*)&xz, (void*)&WhF, (void*)&h0, (void*)&tokens,
                        (void*)&bar};
        hipLaunchCooperativeKernel((void*)lstm_pers_k, dim3(64), dim3(512),
                                   args, 0, stream);
    }
    // ---- layer 1 input projection ----
    cvt_k<<<4096, blk, 0, stream>>>(h0, Ahp, Alp);
    twz_k<<<dim3(128, 32), blk, 0, stream>>>(Wx1, Bh, Bl, 1024, 4096, 0);
    mgemm_k<0><<<dim3(32, 32), blk, 0, stream>>>(Ahp, Alp, Bh, Bl, b1, xz,
                                                 nullptr, 1024, 4096, 0);
    // ---- layer 1 recurrence (persistent) ----
    wprep_k<<<2048, blk, 0, stream>>>(Wh1, (uint4*)WhF, bar);
    {
        void* args[] = {(void*)&xz, (void*)&WhF, (void*)&h1, (void*)&tokens,
                        (void*)&bar};
        hipLaunchCooperativeKernel((void*)lstm_pers_k, dim3(64), dim3(512),
                                   args, 0, stream);
    }
    // ---- vocab projection in two N-halves (bounds ws usage) ----
    cvt_k<<<4096, blk, 0, stream>>>(h1, Ahp, Alp);
    twz_k<<<dim3(500, 32), blk, 0, stream>>>(Wout, Bh, Bl, 1024, 32000, 0);
    mgemm_k<1><<<dim3(125, 32), blk, 0, stream>>>(Ahp, Alp, Bh, Bl, bout, out,
                                                  tokens, 1024, 32000, 0);
    twz_k<<<dim3(500, 32), blk, 0, stream>>>(Wout, Bh, Bl, 1024, 32000, 16000);
    mgemm_k<1><<<dim3(125, 32), blk, 0, stream>>>(Ahp, Alp, Bh, Bl, bout, out,
                                                  tokens, 1024, 32000, 16000);
}

// Round 7
// 5375.210 us; speedup vs baseline: 3.0904x; 1.0099x over previous
//
#include <hip/hip_runtime.h>

#define B_ 16
#define T_ 256
#define E_ 512
#define H_ 1024
#define V_ 32000

typedef float f32x4 __attribute__((ext_vector_type(4)));
typedef short short8 __attribute__((ext_vector_type(8)));

typedef __attribute__((address_space(1))) const void gas_t;
typedef __attribute__((address_space(3))) void las_t;

__device__ __forceinline__ unsigned short f2bf(float x) {
    unsigned int u = __float_as_uint(x);
    u += 0x7FFF + ((u >> 16) & 1);            // RTNE
    return (unsigned short)(u >> 16);
}
__device__ __forceinline__ float bf2f(unsigned short b) {
    return __uint_as_float(((unsigned int)b) << 16);
}

// ---------------------------------------------------------------------------
// Embedding gather fused with bf16 hi/lo split: emb[tokens] -> Ah/Al [4096,512]
// ---------------------------------------------------------------------------
__global__ __launch_bounds__(256)
void gather_cvt_k(const int* __restrict__ tokens, const float* __restrict__ emb,
                  unsigned short* __restrict__ Ah, unsigned short* __restrict__ Al)
{
    int i  = blockIdx.x * 256 + threadIdx.x;   // float4 id; 4096*128 total
    int bt = i >> 7;
    int e4 = i & 127;
    float4 v = ((const float4*)(emb + (size_t)tokens[bt] * E_))[e4];
    ushort4 h, l;
    h.x = f2bf(v.x); l.x = f2bf(v.x - bf2f(h.x));
    h.y = f2bf(v.y); l.y = f2bf(v.y - bf2f(h.y));
    h.z = f2bf(v.z); l.z = f2bf(v.z - bf2f(h.z));
    h.w = f2bf(v.w); l.w = f2bf(v.w - bf2f(h.w));
    ((ushort4*)Ah)[i] = h;
    ((ushort4*)Al)[i] = l;
}

// ---------------------------------------------------------------------------
// fp32 -> bf16 hi/lo split (A activations, row-major, no transpose)
// ---------------------------------------------------------------------------
__global__ __launch_bounds__(256)
void cvt_k(const float* __restrict__ A, unsigned short* __restrict__ Ah,
           unsigned short* __restrict__ Al)
{
    int i = blockIdx.x * 256 + threadIdx.x;    // float4 id
    float4 v = ((const float4*)A)[i];
    ushort4 h, l;
    h.x = f2bf(v.x); l.x = f2bf(v.x - bf2f(h.x));
    h.y = f2bf(v.y); l.y = f2bf(v.y - bf2f(h.y));
    h.z = f2bf(v.z); l.z = f2bf(v.z - bf2f(h.z));
    h.w = f2bf(v.w); l.w = f2bf(v.w - bf2f(h.w));
    ((ushort4*)Ah)[i] = h;
    ((ushort4*)Al)[i] = l;
}

// ---------------------------------------------------------------------------
// Weight transpose + split: W fp32 [K][Nfull], col slice [n0, n0+NS) ->
// Bh/Bl bf16 [NS][K]. 32x32 LDS tiles, +1 pad, coalesced both sides.
// ---------------------------------------------------------------------------
__global__ __launch_bounds__(256)
void twz_k(const float* __restrict__ W, unsigned short* __restrict__ Bh,
           unsigned short* __restrict__ Bl, int Kd, int Nfull, int n0)
{
    __shared__ float tile[32][33];
    int t  = threadIdx.x;
    int tx = t & 31, ty = t >> 5;              // ty 0..7
    int nb = blockIdx.x * 32, kb = blockIdx.y * 32;
    #pragma unroll
    for (int i = 0; i < 4; ++i)
        tile[ty + i * 8][tx] = W[(size_t)(kb + ty + i * 8) * Nfull + n0 + nb + tx];
    __syncthreads();
    #pragma unroll
    for (int i = 0; i < 4; ++i) {
        float v = tile[tx][ty + i * 8];
        unsigned short h = f2bf(v), l = f2bf(v - bf2f(h));
        size_t o = (size_t)(nb + ty + i * 8) * Kd + kb + tx;
        Bh[o] = h; Bl[o] = l;
    }
}

// ---------------------------------------------------------------------------
// Split-bf16 3-pass MFMA GEMM (round-5-verified, unchanged): staging via
// global_load_lds width 16, pre-swizzled source, XOR-swizzled LDS reads.
// ---------------------------------------------------------------------------
template<int DO_MASK>
__global__ __launch_bounds__(256)
void mgemm_k(const unsigned short* __restrict__ Ah, const unsigned short* __restrict__ Al,
             const unsigned short* __restrict__ Bh, const unsigned short* __restrict__ Bl,
             const float* __restrict__ bias, float* __restrict__ C,
             const int* __restrict__ tokens, int K, int ldc, int n0)
{
    __shared__ unsigned short LDSS[4][128 * 64];   // 64 KB: Ah,Al,Bh,Bl planes

    const int tid  = threadIdx.x;
    const int bm   = blockIdx.y * 128;
    const int bn   = blockIdx.x * 128;
    const int w    = tid >> 6, lane = tid & 63;
    const int wm   = (w >> 1) * 64, wn = (w & 1) * 64;
    const int l15  = lane & 15, lhi = lane >> 4;

    const unsigned short* gp = (w == 0) ? Ah : (w == 1) ? Al : (w == 2) ? Bh : Bl;
    const int rb = (w < 2) ? bm : bn;
    const int srow = lane >> 3;
    const int scol = (lane & 7) ^ srow;
    unsigned short* lbase = &LDSS[w][0];

    f32x4 acc[4][4];
    #pragma unroll
    for (int mi = 0; mi < 4; ++mi)
        #pragma unroll
        for (int ni = 0; ni < 4; ++ni) {
            f32x4 z = {0.f, 0.f, 0.f, 0.f};
            acc[mi][ni] = z;
        }

    for (int kt = 0; kt < K; kt += 64) {
        #pragma unroll
        for (int c = 0; c < 16; ++c) {
            const unsigned short* src =
                gp + (size_t)(rb + c * 8 + srow) * K + kt + scol * 8;
            __builtin_amdgcn_global_load_lds((gas_t*)src,
                                             (las_t*)(lbase + c * 512), 16, 0, 0);
        }
        __syncthreads();
        #pragma unroll
        for (int ks = 0; ks < 2; ++ks) {
            short8 ah[4], al[4], bh[4], bl[4];
            const int s = ks * 4 + lhi;
            #pragma unroll
            for (int mi = 0; mi < 4; ++mi) {
                int m = wm + mi * 16 + l15;
                int off = m * 64 + ((s ^ (m & 7)) * 8);
                ah[mi] = *(const short8*)(&LDSS[0][off]);
                al[mi] = *(const short8*)(&LDSS[1][off]);
            }
            #pragma unroll
            for (int ni = 0; ni < 4; ++ni) {
                int n = wn + ni * 16 + l15;
                int off = n * 64 + ((s ^ (n & 7)) * 8);
                bh[ni] = *(const short8*)(&LDSS[2][off]);
                bl[ni] = *(const short8*)(&LDSS[3][off]);
            }
            #pragma unroll
            for (int mi = 0; mi < 4; ++mi)
                #pragma unroll
                for (int ni = 0; ni < 4; ++ni) {
                    acc[mi][ni] = __builtin_amdgcn_mfma_f32_16x16x32_bf16(
                        ah[mi], bh[ni], acc[mi][ni], 0, 0, 0);
                    acc[mi][ni] = __builtin_amdgcn_mfma_f32_16x16x32_bf16(
                        ah[mi], bl[ni], acc[mi][ni], 0, 0, 0);
                    acc[mi][ni] = __builtin_amdgcn_mfma_f32_16x16x32_bf16(
                        al[mi], bh[ni], acc[mi][ni], 0, 0, 0);
                }
        }
        __syncthreads();
    }

    #pragma unroll
    for (int mi = 0; mi < 4; ++mi) {
        #pragma unroll
        for (int r = 0; r < 4; ++r) {
            int row = bm + wm + mi * 16 + lhi * 4 + r;
            bool msk = true;
            if (DO_MASK) msk = (tokens[row] != 0);
            #pragma unroll
            for (int ni = 0; ni < 4; ++ni) {
                int col = bn + wn + ni * 16 + l15;
                float v = acc[mi][ni][r] + bias[n0 + col];
                if (DO_MASK && !msk) v = ((n0 + col) == 0) ? 1.f : 0.f;
                C[(size_t)row * ldc + n0 + col] = v;
            }
        }
    }
}

// ---------------------------------------------------------------------------
// Wh [1024][4096] fp32 -> register-fragment image WhF (bf16 hi/lo B-frags).
// Also resets the 64 per-block barrier flags for the persistent launch.
// ---------------------------------------------------------------------------
__global__ __launch_bounds__(256)
void wprep_k(const float* __restrict__ Wh, uint4* __restrict__ WhF,
             unsigned* __restrict__ flags)
{
    int flat = blockIdx.x * 256 + threadIdx.x;      // 0 .. 524287
    if (flat < 64) flags[flat * 16] = 0;
    int l  = flat & 63;
    int kf = (flat >> 6) & 3;
    int ct = (flat >> 8) & 3;
    int w  = (flat >> 10) & 7;
    int bx = flat >> 13;                            // 0..63
    int k0  = w * 128 + kf * 32 + 8 * (l >> 4);
    int col = ct * H_ + bx * 16 + (l & 15);
    unsigned short hi[8], lo[8];
    #pragma unroll
    for (int j = 0; j < 8; ++j) {
        float v = Wh[(size_t)(k0 + j) * (4 * H_) + col];
        hi[j] = f2bf(v); lo[j] = f2bf(v - bf2f(hi[j]));
    }
    size_t base = ((((size_t)bx * 8 + w) * 4 + ct) * 4 + kf) * 2;
    WhF[(base + 0) * 64 + l] = *(uint4*)hi;
    WhF[(base + 1) * 64 + l] = *(uint4*)lo;
}

// ---------------------------------------------------------------------------
// Persistent MFMA LSTM layer. 64 blocks x 512 threads (cooperative).
// Round-7 change: contention-free flag barrier. Each block stores its OWN
// flag (64B-spread lines, parallel at MALL — no serialized RMW like the
// round-6 central counter). Wave 0: gates -> h stores -> vmcnt(0) drain ->
// flag store -> poll all 64 flags (lane l reads flags[l*16], __all >= t+1).
// Waves 1-7 wait at __syncthreads (no poll traffic). h crosses XCDs via
// relaxed agent-scope atomics (MALL), read-only xz/tokens stay cached.
// ---------------------------------------------------------------------------
__global__ __launch_bounds__(512, 2)
void lstm_pers_k(const float* __restrict__ xz,   // [B*T][4H]
                 const uint4* __restrict__ WhF,
                 float* __restrict__ hseq,       // [B*T][H]
                 const int* __restrict__ tokens,
                 unsigned* __restrict__ flags)
{
    __shared__ f32x4 Rs[32 * 64];                 // 32 KB: [(ct*8+w)*64 + l]

    const int tid = threadIdx.x;
    const int bx  = blockIdx.x;                   // 0..63
    const int w   = tid >> 6;
    const int l   = tid & 63;
    const int l15 = l & 15, lhi = l >> 4;

    // one-time load of register-resident Wh fragments (coalesced)
    short8 Bhi[4][4], Blo[4][4];
    {
        const uint4* p = WhF + (((size_t)bx * 8 + w) * 32) * 64;
        #pragma unroll
        for (int ct = 0; ct < 4; ++ct)
            #pragma unroll
            for (int kf = 0; kf < 4; ++kf) {
                uint4 hv = p[((ct * 4 + kf) * 2 + 0) * 64 + l];
                uint4 lv = p[((ct * 4 + kf) * 2 + 1) * 64 + l];
                Bhi[ct][kf] = *(short8*)&hv;
                Blo[ct][kf] = *(short8*)&lv;
            }
    }

    f32x4 c4 = {0.f, 0.f, 0.f, 0.f};
    f32x4 h4 = {0.f, 0.f, 0.f, 0.f};
    const int u = bx * 16 + l15;                  // wave-0 gate-phase unit

    for (int t = 0; t < T_; ++t) {
        if (t > 0) {
            f32x4 acc0 = {0.f,0.f,0.f,0.f}, acc1 = acc0, acc2 = acc0, acc3 = acc0;
            const float* hrow = hseq + ((size_t)(l15 * T_ + t - 1)) * H_
                              + w * 128 + 8 * lhi;
            #pragma unroll
            for (int kf = 0; kf < 4; ++kf) {
                const unsigned long long* hp =
                    (const unsigned long long*)(hrow + kf * 32);
                float hv[8];
                #pragma unroll
                for (int q = 0; q < 4; ++q) {
                    unsigned long long d = __hip_atomic_load(hp + q,
                        __ATOMIC_RELAXED, __HIP_MEMORY_SCOPE_AGENT);
                    hv[q * 2]     = __uint_as_float((unsigned)d);
                    hv[q * 2 + 1] = __uint_as_float((unsigned)(d >> 32));
                }
                unsigned short hh[8], hl[8];
                #pragma unroll
                for (int j = 0; j < 8; ++j) {
                    hh[j] = f2bf(hv[j]);
                    hl[j] = f2bf(hv[j] - bf2f(hh[j]));
                }
                short8 ah = *(short8*)hh, al = *(short8*)hl;
                acc0 = __builtin_amdgcn_mfma_f32_16x16x32_bf16(ah, Bhi[0][kf], acc0, 0,0,0);
                acc0 = __builtin_amdgcn_mfma_f32_16x16x32_bf16(ah, Blo[0][kf], acc0, 0,0,0);
                acc0 = __builtin_amdgcn_mfma_f32_16x16x32_bf16(al, Bhi[0][kf], acc0, 0,0,0);
                acc1 = __builtin_amdgcn_mfma_f32_16x16x32_bf16(ah, Bhi[1][kf], acc1, 0,0,0);
                acc1 = __builtin_amdgcn_mfma_f32_16x16x32_bf16(ah, Blo[1][kf], acc1, 0,0,0);
                acc1 = __builtin_amdgcn_mfma_f32_16x16x32_bf16(al, Bhi[1][kf], acc1, 0,0,0);
                acc2 = __builtin_amdgcn_mfma_f32_16x16x32_bf16(ah, Bhi[2][kf], acc2, 0,0,0);
                acc2 = __builtin_amdgcn_mfma_f32_16x16x32_bf16(ah, Blo[2][kf], acc2, 0,0,0);
                acc2 = __builtin_amdgcn_mfma_f32_16x16x32_bf16(al, Bhi[2][kf], acc2, 0,0,0);
                acc3 = __builtin_amdgcn_mfma_f32_16x16x32_bf16(ah, Bhi[3][kf], acc3, 0,0,0);
                acc3 = __builtin_amdgcn_mfma_f32_16x16x32_bf16(ah, Blo[3][kf], acc3, 0,0,0);
                acc3 = __builtin_amdgcn_mfma_f32_16x16x32_bf16(al, Bhi[3][kf], acc3, 0,0,0);
            }
            Rs[(0 * 8 + w) * 64 + l] = acc0;
            Rs[(1 * 8 + w) * 64 + l] = acc1;
            Rs[(2 * 8 + w) * 64 + l] = acc2;
            Rs[(3 * 8 + w) * 64 + l] = acc3;
        }
        __syncthreads();

        if (w == 0) {
            f32x4 z4[4];
            #pragma unroll
            for (int ct = 0; ct < 4; ++ct) {
                f32x4 s = {0.f, 0.f, 0.f, 0.f};
                if (t > 0) {
                    #pragma unroll
                    for (int w2 = 0; w2 < 8; ++w2) {
                        f32x4 v = Rs[(ct * 8 + w2) * 64 + l];
                        s[0] += v[0]; s[1] += v[1]; s[2] += v[2]; s[3] += v[3];
                    }
                }
                z4[ct] = s;
            }
            #pragma unroll
            for (int r = 0; r < 4; ++r) {
                int b = lhi * 4 + r;
                size_t bt = (size_t)b * T_ + t;
                float zi = z4[0][r] + xz[bt * 4096 + 0 * H_ + u];
                float zf = z4[1][r] + xz[bt * 4096 + 1 * H_ + u];
                float zg = z4[2][r] + xz[bt * 4096 + 2 * H_ + u];
                float zo = z4[3][r] + xz[bt * 4096 + 3 * H_ + u];
                float i_ = 1.f / (1.f + expf(-zi));
                float f_ = 1.f / (1.f + expf(-zf));
                float g_ = tanhf(zg);
                float o_ = 1.f / (1.f + expf(-zo));
                float c_new = f_ * c4[r] + i_ * g_;
                float h_new = o_ * tanhf(c_new);
                bool  m  = (tokens[bt] != 0);
                float h2 = m ? h_new : h4[r];
                float c2 = m ? c_new : c4[r];
                c4[r] = c2;
                h4[r] = h2;
                __hip_atomic_store(&hseq[bt * H_ + u], h2,
                                   __ATOMIC_RELAXED, __HIP_MEMORY_SCOPE_AGENT);
            }
            if (t + 1 < T_) {
                // drain h stores, publish own flag, poll all 64 (no RMW)
                asm volatile("s_waitcnt vmcnt(0)" ::: "memory");
                if (l == 0)
                    __hip_atomic_store(&flags[bx * 16], (unsigned)(t + 1),
                                       __ATOMIC_RELAXED, __HIP_MEMORY_SCOPE_AGENT);
                const unsigned tgt = (unsigned)(t + 1);
                while (true) {
                    unsigned fv = __hip_atomic_load(&flags[l * 16],
                        __ATOMIC_RELAXED, __HIP_MEMORY_SCOPE_AGENT);
                    if (__all(fv >= tgt)) break;
                    __builtin_amdgcn_s_sleep(1);
                }
            }
        }
        __syncthreads();                          // releases waves 1-7
    }
}

// ---------------------------------------------------------------------------
extern "C" void kernel_launch(void* const* d_in, const int* in_sizes, int n_in,
                              void* d_out, int out_size, void* d_ws, size_t ws_size,
                              hipStream_t stream)
{
    const int*   tokens = (const int*)d_in[0];
    const float* emb    = (const float*)d_in[1];
    const float* Wx0    = (const float*)d_in[2];
    const float* Wh0    = (const float*)d_in[3];
    const float* b0     = (const float*)d_in[4];
    const float* Wx1    = (const float*)d_in[5];
    const float* Wh1    = (const float*)d_in[6];
    const float* b1     = (const float*)d_in[7];
    const float* Wout   = (const float*)d_in[8];
    const float* bout   = (const float*)d_in[9];
    float* out = (float*)d_out;

    // d_ws: bf16 planes (~82.3 MB) + 64 spread barrier flags (4 KB)
    unsigned short* wsu = (unsigned short*)d_ws;
    const size_t BPL = (size_t)16000 * 1024;          // B-plane slot (shorts)
    const size_t AP  = (size_t)4096 * 1024;           // A-plane slot (shorts)
    unsigned short* Bh  = wsu;
    unsigned short* Bl  = wsu + BPL;
    unsigned short* Ahp = wsu + 2 * BPL;
    unsigned short* Alp = Ahp + AP;
    unsigned* flags = (unsigned*)(wsu + 2 * BPL + 2 * AP);

    // d_out head used as fp32 scratch; all dead before final GEMM writes logits.
    float* f   = (float*)d_out;
    float* xz  = f;                                   // 16.78M floats
    float* WhF = xz + (size_t)4096 * 4096;            // 4.19M (frag image)
    float* h0  = WhF + (size_t)1024 * 4096;           // 4.19M
    float* h1  = h0 + (size_t)4096 * 1024;            // 4.19M

    dim3 blk(256);

    // ---- layer 0 input projection ----
    gather_cvt_k<<<2048, blk, 0, stream>>>(tokens, emb, Ahp, Alp);
    twz_k<<<dim3(128, 16), blk, 0, stream>>>(Wx0, Bh, Bl, 512, 4096, 0);
    mgemm_k<0><<<dim3(32, 32), blk, 0, stream>>>(Ahp, Alp, Bh, Bl, b0, xz,
                                                 nullptr, 512, 4096, 0);
    // ---- layer 0 recurrence (persistent) ----
    wprep_k<<<2048, blk, 0, stream>>>(Wh0, (uint4*)WhF, flags);
    {
        void* args[] = {(void*)&xz, (void*)&WhF, (void*)&h0, (void*)&tokens,
                        (void*)&flags};
        hipLaunchCooperativeKernel((void*)lstm_pers_k, dim3(64), dim3(512),
                                   args, 0, stream);
    }
    // ---- layer 1 input projection ----
    cvt_k<<<4096, blk, 0, stream>>>(h0, Ahp, Alp);
    twz_k<<<dim3(128, 32), blk, 0, stream>>>(Wx1, Bh, Bl, 1024, 4096, 0);
    mgemm_k<0><<<dim3(32, 32), blk, 0, stream>>>(Ahp, Alp, Bh, Bl, b1, xz,
                                                 nullptr, 1024, 4096, 0);
    // ---- layer 1 recurrence (persistent) ----
    wprep_k<<<2048, blk, 0, stream>>>(Wh1, (uint4*)WhF, flags);
    {
        void* args[] = {(void*)&xz, (void*)&WhF, (void*)&h1, (void*)&tokens,
                        (void*)&flags};
        hipLaunchCooperativeKernel((void*)lstm_pers_k, dim3(64), dim3(512),
                                   args, 0, stream);
    }
    // ---- vocab projection in two N-halves (bounds ws usage) ----
    cvt_k<<<4096, blk, 0, stream>>>(h1, Ahp, Alp);
    twz_k<<<dim3(500, 32), blk, 0, stream>>>(Wout, Bh, Bl, 1024, 32000, 0);
    mgemm_k<1><<<dim3(125, 32), blk, 0, stream>>>(Ahp, Alp, Bh, Bl, bout, out,
                                                  tokens, 1024, 32000, 0);
    twz_k<<<dim3(500, 32), blk, 0, stream>>>(Wout, Bh, Bl, 1024, 32000, 16000);
    mgemm_k<1><<<dim3(125, 32), blk, 0, stream>>>(Ahp, Alp, Bh, Bl, bout, out,
                                                  tokens, 1024, 32000, 16000);
}